// Round 5
// baseline (265.262 us; speedup 1.0000x reference)
//
#include <hip/hip_runtime.h>
#include <hip/hip_bf16.h>
#include <hip/hip_cooperative_groups.h>

namespace cg = cooperative_groups;

// Problem constants (B=1, N=2048, D=1024, H=16, HD=64; NO=74 offsets)
#define SEQ_N 2048
#define DIM   1024
#define NHEAD 16
#define HDIM  64
#define LDQ   4096   // qkvg row stride: [q | k | v | gatepre]
#define NOFF  74     // 65 dense (0..64) + 9 dyadic
#define NDENSE 65
#define NJ    224    // 80 dense rows + 9*16 dyadic rows
#define NT    16     // n-rows per attention block
#define PST   232    // Pd row stride (padded, 16B-aligned)
#define QST   88     // Qbuf row stride (16B-aligned)

typedef __attribute__((ext_vector_type(8)))  __bf16 bv8;
typedef __attribute__((ext_vector_type(4)))  __bf16 bv4;
typedef __attribute__((ext_vector_type(4)))  float  f32x4;
typedef __attribute__((ext_vector_type(16))) float  f32x16;

typedef __attribute__((address_space(3))) void as3_void;
typedef __attribute__((address_space(1))) void as1_void;

// async global->LDS 16B copy. LDS dest must be wave-uniform base + lane*16.
__device__ __forceinline__ void async16(const void* g, void* l) {
  __builtin_amdgcn_global_load_lds((as1_void*)(unsigned long long)g,
                                   (as3_void*)l, 16, 0, 0);
}

#define E1 (SEQ_N * DIM)            // x
#define E2 (E1 + 3 * DIM * DIM)     // + Wqkv
#define E3 (E2 + DIM * DIM)         // + Wgate
#define E4 (E3 + DIM * DIM)         // + Wout

// ---------------------------------------------------------------------------
// GEMM device body: C = A[MxK] * B[NoutxK]^T + bias, bf16 in, fp32 accum.
// BM_xBN_ tile, WMxWN waves, KT_-step double-buffered LDS with prefetch-
// before-compute (T3-lite). m97 staging (async16 w=16) + global-side XOR
// chunk-swizzle. Inner: v_mfma_f32_32x32x16_bf16 (A/B: m=lane&31,
// k=8*(lane>>5)+i; C/D: col=lane&31, row=(reg&3)+8*(reg>>2)+4*(lane>>5)
// [m74/m101 verified]). T1 XCD chunked swizzle (bijective, NWG%8==0),
// column-major work order. K-order: KT=64 ascending -> numerics unchanged.
// ---------------------------------------------------------------------------
template <int BM_, int BN_, int KT_, int WM, int WN, int GX, int GY, typename OutT>
__device__ __forceinline__ void gemm_body(
    char* ldsb, int bid, int tid,
    const __bf16* __restrict__ A, const __bf16* __restrict__ B1,
    const __bf16* __restrict__ B2, const float* __restrict__ bias1,
    const float* __restrict__ bias2, int Nsplit,
    OutT* __restrict__ C, int ldc, int K) {
  constexpr int NTHR = WM * WN * 64;
  constexpr int NI  = BM_ / (WM * 32);     // 32-row tiles per wave
  constexpr int NJ_ = BN_ / (WN * 32);     // 32-col tiles per wave
  constexpr int CA = BM_ * KT_ / 8;        // A 16B-chunks per step
  constexpr int CB = BN_ * KT_ / 8;        // B 16B-chunks per step
  constexpr int CT = CA + CB;
  constexpr int CPR = KT_ / 8;             // chunks per row
  constexpr int BUF = (BM_ + BN_) * KT_;   // elems per dbuf half
  static_assert(CA % NTHR == 0 && CT % NTHR == 0, "stage divisibility");

  __bf16* smem = (__bf16*)ldsb;

  const int lane = tid & 63;
  const int wave = tid >> 6;
  const int wm = wave / WN, wn = wave % WN;
  const int m31 = lane & 31;
  const int h1  = lane >> 5;
  const int l7  = lane & 7;

  constexpr int NWG = GX * GY;
  const int work = (bid & 7) * (NWG >> 3) + (bid >> 3);
  const int bn0 = (work / GY) * BN_;
  const int bm0 = (work % GY) * BM_;

  const __bf16* Bp;
  const float* biasp;
  if (bn0 < Nsplit) { Bp = B1 + (size_t)bn0 * K;            biasp = bias1 + bn0; }
  else              { Bp = B2 + (size_t)(bn0 - Nsplit) * K; biasp = bias2 + (bn0 - Nsplit); }
  const __bf16* Ap = A + (size_t)bm0 * K;

  f32x16 acc[NI][NJ_] = {};

  auto stage = [&](int ktoff, int sel_) {
#pragma unroll
    for (int c0 = 0; c0 < CT; c0 += NTHR) {
      int c = c0 + tid;
      if (c < CA) {
        int rr = c / CPR, qq = c % CPR;
        int qs = qq ^ (rr & 7);
        async16(Ap + (size_t)rr * K + ktoff + qs * 8, smem + sel_ * BUF + c * 8);
      } else {
        int cb = c - CA;
        int rr = cb / CPR, qq = cb % CPR;
        int qs = qq ^ (rr & 7);
        async16(Bp + (size_t)rr * K + ktoff + qs * 8,
                smem + sel_ * BUF + BM_ * KT_ + cb * 8);
      }
    }
  };

  stage(0, 0);
  __syncthreads();

  const int NSTEP = K / KT_;
  int sel = 0;
  for (int t = 0; t < NSTEP; ++t) {
    if (t + 1 < NSTEP) stage((t + 1) * KT_, sel ^ 1);

#pragma unroll
    for (int kk = 0; kk < KT_ / 16; ++kk) {
      const int qs = ((kk * 2 + h1) ^ l7) * 8;
      bv8 af[NI], bfr[NJ_];
#pragma unroll
      for (int i = 0; i < NI; ++i)
        af[i] = *(const bv8*)(smem + sel * BUF +
                              (wm * (BM_ / WM) + i * 32 + m31) * KT_ + qs);
#pragma unroll
      for (int j = 0; j < NJ_; ++j)
        bfr[j] = *(const bv8*)(smem + sel * BUF + BM_ * KT_ +
                               (wn * (BN_ / WN) + j * 32 + m31) * KT_ + qs);
#pragma unroll
      for (int i = 0; i < NI; ++i)
#pragma unroll
        for (int j = 0; j < NJ_; ++j)
          acc[i][j] = __builtin_amdgcn_mfma_f32_32x32x16_bf16(af[i], bfr[j], acc[i][j], 0, 0, 0);
    }

    __syncthreads();
    sel ^= 1;
  }

#pragma unroll
  for (int i = 0; i < NI; ++i) {
#pragma unroll
    for (int j = 0; j < NJ_; ++j) {
      int ccol = wn * (BN_ / WN) + j * 32 + m31;
      float b = biasp[ccol];
#pragma unroll
      for (int reg = 0; reg < 16; ++reg) {
        int row = bm0 + wm * (BM_ / WM) + i * 32 + (reg & 3) + 8 * (reg >> 2) + 4 * h1;
        C[(size_t)row * ldc + bn0 + ccol] = (OutT)(acc[i][j][reg] + b);
      }
    }
  }
}

// ---------------------------------------------------------------------------
// Attention tile device body (one (n0,h) work item, 256 threads tid2=0..255).
// Identical algorithm to the R0-verified attn_mfma: K staged swizzled, V
// staged SUBTILED [j/4][d/16][4][16] (source-side permutation, linear dest,
// m173), Phase-3 B-fragment via ds_read_b64_tr_b16 (T10).
// LDS slab layout (44096 B): KVbuf@0(28672) Qbuf@28672(2816) Sbuf@31488(5120)
// Pd@36608(7424) inv_l@44032(64).
// ---------------------------------------------------------------------------
__device__ __forceinline__ void attn_tile(
    const __bf16* __restrict__ qkv, const float* __restrict__ pos_bias,
    const int* __restrict__ offsets, __bf16* __restrict__ fg,
    char* ldsh, int n0, int h, int tid2) {
  __bf16* KVbuf = (__bf16*)ldsh;
  __bf16* Qbuf  = (__bf16*)(ldsh + 28672);
  float (*Sbuf)[80] = (float(*)[80])(ldsh + 31488);
  __bf16* Pd    = (__bf16*)(ldsh + 36608);
  float* inv_l  = (float*)(ldsh + 44032);

  const int lane = tid2 & 63;
  const int w = tid2 >> 6;
  const int fr = lane & 15, fq = lane >> 4;
  const int fr7 = fr & 7;
  const int ch = lane & 7;
  const int rowin = lane >> 3;

  // --- Phase 0: stage Q, zero Pd, async-stage K (swizzled chunks) ---
  if (tid2 < 128) {
    int ni = tid2 >> 3, cq = tid2 & 7;
    bv8 q = *(const bv8*)(qkv + (size_t)(n0 + ni) * LDQ + h * HDIM + cq * 8);
    *(bv8*)(Qbuf + ni * QST + cq * 8) = q;
  }
#pragma unroll
  for (int c0 = 0; c0 < NT * PST / 8; c0 += 256) {
    int c = c0 + tid2;
    if (c < NT * PST / 8) *(uint4*)(Pd + c * 8) = make_uint4(0, 0, 0, 0);
  }
  {
    int chs = ch ^ rowin;
#pragma unroll
    for (int it = 0; it < 7; ++it) {
      int jbase = it * 32 + w * 8;
      int j = jbase + rowin;
      int g;
      if (j < 80) g = n0 - 64 + j;
      else { int jj = j - 80; g = n0 - offsets[NDENSE + (jj >> 4)] + (jj & 15); }
      if (g < 0) g = 0;   // clamp; masked later
      async16(qkv + (size_t)g * LDQ + DIM + h * HDIM + chs * 8,
              KVbuf + jbase * HDIM + lane * 8);
    }
  }
  __syncthreads();

  // --- Phase 1: scores via MFMA, scatter banded entries to Sbuf ---
  for (int jb = w; jb < 14; jb += 4) {
    f32x4 acc = {};
#pragma unroll
    for (int kk = 0; kk < 2; ++kk) {
      bv8 a = *(const bv8*)(Qbuf + fr * QST + kk * 32 + fq * 8);
      bv8 b = *(const bv8*)(KVbuf + (jb * 16 + fr) * HDIM + ((kk * 4 + fq) ^ fr7) * 8);
      acc = __builtin_amdgcn_mfma_f32_16x16x32_bf16(a, b, acc, 0, 0, 0);
    }
    int j = jb * 16 + fr;
    if (jb < 5) {
      bool gvalid = (n0 - 64 + j) >= 0;
#pragma unroll
      for (int r = 0; r < 4; ++r) {
        int ni = fq * 4 + r;
        int o = ni + 64 - j;
        if (o >= 0 && o < NDENSE)
          Sbuf[ni][o] = gvalid ? acc[r] : -3.0e38f;
      }
    } else {
      int jj = j - 80;
      int s = jj >> 4, tni = jj & 15;
      int r = tni - fq * 4;
      if (r >= 0 && r < 4) {
        bool gvalid = (n0 + tni - offsets[NDENSE + s]) >= 0;
        Sbuf[tni][NDENSE + s] = gvalid ? acc[r] : -3.0e38f;
      }
    }
  }
  __syncthreads();   // all K reads done -> KVbuf reusable; Sbuf published

  // --- stage V into KVbuf, SUBTILED layout; overlaps Phase-2 softmax ---
  {
#pragma unroll
    for (int it = 0; it < 7; ++it) {
      int jbase = it * 32 + w * 8;
      int jv = jbase + (lane >> 5) * 4 + ((lane >> 1) & 3);
      int dv = ((lane >> 3) & 3) * 16 + (lane & 1) * 8;
      int g;
      if (jv < 80) g = n0 - 64 + jv;
      else { int jj = jv - 80; g = n0 - offsets[NDENSE + (jj >> 4)] + (jj & 15); }
      if (g < 0) g = 0;
      async16(qkv + (size_t)g * LDQ + 2 * DIM + h * HDIM + dv,
              KVbuf + jbase * HDIM + lane * 8);
    }
  }

  // --- Phase 2: softmax (16 threads per row), banded P -> Pd (bf16) ---
  {
    int t = tid2 & 15, ni = tid2 >> 4;
    float sc5[5];
    float m = -3.0e38f;
#pragma unroll
    for (int k = 0; k < 5; ++k) {
      int o = t + k * 16;
      float v = -3.0e38f;
      if (o < NOFF) {
        float raw = Sbuf[ni][o];
        if (raw > -1.0e38f) v = raw * 0.125f + pos_bias[o * NHEAD + h];
      }
      sc5[k] = v;
      m = fmaxf(m, v);
    }
#pragma unroll
    for (int d = 1; d < 16; d <<= 1) m = fmaxf(m, __shfl_xor(m, d));
    float sum = 0.f;
#pragma unroll
    for (int k = 0; k < 5; ++k) {
      int o = t + k * 16;
      if (o < NOFF && sc5[k] > -1.0e38f) {
        float e = __expf(sc5[k] - m);
        sum += e;
        int j = (o < NDENSE) ? (ni + 64 - o) : (80 + (o - NDENSE) * 16 + ni);
        Pd[ni * PST + j] = (__bf16)e;
      }
    }
#pragma unroll
    for (int d = 1; d < 16; d <<= 1) sum += __shfl_xor(sum, d);
    if (t == 0) inv_l[ni] = 1.f / sum;
  }
  __syncthreads();   // drains V async16s (vmcnt 0) + publishes Pd/inv_l

  // --- Phase 3: PV via MFMA, B-fragment via 2x ds_read_b64_tr_b16 per kt ---
  {
    const int db = w;
    const unsigned vb0 = (unsigned)(size_t)(as3_void*)KVbuf
                       + fq * 1024 + db * 128 + fr * 8;
    f32x4 acc = {};
#pragma unroll
    for (int kt = 0; kt < 7; ++kt) {
      bv8 a = *(const bv8*)(Pd + fr * PST + kt * 32 + fq * 8);
      bv4 lo, hi;
      asm volatile("ds_read_b64_tr_b16 %0, %2 offset:%3\n\t"
                   "ds_read_b64_tr_b16 %1, %2 offset:%4\n\t"
                   "s_waitcnt lgkmcnt(0)"
                   : "=&v"(lo), "=&v"(hi)
                   : "v"(vb0), "i"(kt * 4096), "i"(kt * 4096 + 512));
      bv8 b;
#pragma unroll
      for (int jj = 0; jj < 4; ++jj) { b[jj] = lo[jj]; b[4 + jj] = hi[jj]; }
      acc = __builtin_amdgcn_mfma_f32_16x16x32_bf16(a, b, acc, 0, 0, 0);
    }
    int d = db * 16 + fr;
#pragma unroll
    for (int r = 0; r < 4; ++r) {
      int ni = fq * 4 + r;
      float o = acc[r] * inv_l[ni];
      float gp = (float)qkv[(size_t)(n0 + ni) * LDQ + 3 * DIM + h * HDIM + d];
      float gate = 1.f / (1.f + __expf(-gp));
      fg[(size_t)(n0 + ni) * DIM + h * HDIM + d] = (__bf16)(o * gate);
    }
  }
}

// ---------------------------------------------------------------------------
// FUSED cooperative kernel: cvt -> gemm1 -> attn -> gemm3, one dispatch.
// 256 blocks x 512 threads, 96 KB LDS -> exactly 1 block/CU co-resident.
// Attention: 8 items/block = 4 rounds x 2 concurrent 256-thread halves in
// disjoint 48 KB LDS slabs (barrier counts uniform across halves).
// ---------------------------------------------------------------------------
__global__ __launch_bounds__(512, 2) void fused_all(
    const float* __restrict__ x, const float* __restrict__ Wqkv,
    const float* __restrict__ bqkv, const float* __restrict__ Wgate,
    const float* __restrict__ bgate, const float* __restrict__ Wout,
    const float* __restrict__ bout, const float* __restrict__ pos_bias,
    const int* __restrict__ offsets, float* __restrict__ out,
    __bf16* __restrict__ ws) {
  __shared__ __attribute__((aligned(16))) char lds[98304];
  const int tid = threadIdx.x;
  const int bid = blockIdx.x;

  __bf16* xb       = ws;
  __bf16* Wqkvb    = xb    + (size_t)SEQ_N * DIM;
  __bf16* Wgateb   = Wqkvb + (size_t)3 * DIM * DIM;
  __bf16* Woutb    = Wgateb + (size_t)DIM * DIM;
  __bf16* qkvg     = Woutb + (size_t)DIM * DIM;
  __bf16* flatgate = qkvg  + (size_t)SEQ_N * LDQ;

  cg::grid_group grid = cg::this_grid();

  // --- Phase A: fp32 -> bf16 (7 exact grid-stride passes, 8 elems/thread) ---
  {
    const int gt = bid * 512 + tid;            // 0..131071
#pragma unroll
    for (int it = 0; it < 7; ++it) {
      long i = ((long)(it * 131072 + gt)) * 8; // E4 = 7*131072*8 exactly
      const float* s; long o;
      if (i < E1)      { s = x;     o = i; }
      else if (i < E2) { s = Wqkv;  o = i - E1; }
      else if (i < E3) { s = Wgate; o = i - E2; }
      else             { s = Wout;  o = i - E3; }
      float4 v0 = *(const float4*)(s + o);
      float4 v1 = *(const float4*)(s + o + 4);
      bv8 ov;
      ov[0] = (__bf16)v0.x; ov[1] = (__bf16)v0.y; ov[2] = (__bf16)v0.z; ov[3] = (__bf16)v0.w;
      ov[4] = (__bf16)v1.x; ov[5] = (__bf16)v1.y; ov[6] = (__bf16)v1.z; ov[7] = (__bf16)v1.w;
      *(bv8*)(ws + i) = ov;
    }
  }
  grid.sync();

  // --- Phase B: gemm1 [qkv|gate_pre] = x @ [Wqkv;Wgate]^T + bias ---
  gemm_body<128, 256, 64, 2, 4, 16, 16, __bf16>(
      lds, bid, tid, xb, Wqkvb, Wgateb, bqkv, bgate, 3 * DIM, qkvg, LDQ, DIM);
  grid.sync();

  // --- Phase C: attention + gate (8 work items per block) ---
  {
    const int half = tid >> 8;
    const int tid2 = tid & 255;
    char* ldsh = lds + half * 49152;
    for (int r = 0; r < 4; ++r) {
      int widx = bid * 8 + r * 2 + half;       // 0..2047 bijective
      attn_tile(qkvg, pos_bias, offsets, flatgate, ldsh,
                (widx >> 4) * NT, widx & 15, tid2);
      __syncthreads();
    }
  }
  grid.sync();

  // --- Phase D: out = flatgate @ Wout^T + bout ---
  gemm_body<64, 128, 64, 2, 4, 8, 32, float>(
      lds, bid, tid, flatgate, Woutb, Woutb, bout, bout, DIM, out, DIM, DIM);
}

// ---------------------------------------------------------------------------
// Fallback standalone kernels (used only if cooperative launch fails).
// ---------------------------------------------------------------------------
__global__ __launch_bounds__(256) void cvt_all(
    const float* __restrict__ x, const float* __restrict__ wqkv,
    const float* __restrict__ wgate, const float* __restrict__ wout,
    __bf16* __restrict__ dst) {
  long i = ((long)blockIdx.x * 256 + threadIdx.x) * 8;
  if (i >= E4) return;
  const float* s; long o;
  if (i < E1)      { s = x;     o = i; }
  else if (i < E2) { s = wqkv;  o = i - E1; }
  else if (i < E3) { s = wgate; o = i - E2; }
  else             { s = wout;  o = i - E3; }
  float4 v0 = *(const float4*)(s + o);
  float4 v1 = *(const float4*)(s + o + 4);
  bv8 ov;
  ov[0] = (__bf16)v0.x; ov[1] = (__bf16)v0.y; ov[2] = (__bf16)v0.z; ov[3] = (__bf16)v0.w;
  ov[4] = (__bf16)v1.x; ov[5] = (__bf16)v1.y; ov[6] = (__bf16)v1.z; ov[7] = (__bf16)v1.w;
  *(bv8*)(dst + i) = ov;
}

template <int BM_, int BN_, int KT_, int WM, int WN, int GX, int GY, typename OutT>
__global__ __launch_bounds__(WM * WN * 64) void gemm_bt2(
    const __bf16* __restrict__ A, const __bf16* __restrict__ B1,
    const __bf16* __restrict__ B2, const float* __restrict__ bias1,
    const float* __restrict__ bias2, int Nsplit,
    OutT* __restrict__ C, int ldc, int K) {
  __shared__ __attribute__((aligned(16))) char lds[2 * (BM_ + BN_) * KT_ * 2];
  gemm_body<BM_, BN_, KT_, WM, WN, GX, GY, OutT>(
      lds, blockIdx.y * GX + blockIdx.x, threadIdx.x,
      A, B1, B2, bias1, bias2, Nsplit, C, ldc, K);
}

__global__ __launch_bounds__(256) void attn_mfma(
    const __bf16* __restrict__ qkv, const float* __restrict__ pos_bias,
    const int* __restrict__ offsets, __bf16* __restrict__ fg) {
  __shared__ __attribute__((aligned(16))) char lds[44096];
  attn_tile(qkv, pos_bias, offsets, fg, lds,
            (blockIdx.x >> 4) * NT, blockIdx.x & 15, threadIdx.x);
}

// ---------------------------------------------------------------------------
extern "C" void kernel_launch(void* const* d_in, const int* in_sizes, int n_in,
                              void* d_out, int out_size, void* d_ws, size_t ws_size,
                              hipStream_t stream) {
  const float* x        = (const float*)d_in[0];
  const float* Wqkv     = (const float*)d_in[1];
  const float* bqkv     = (const float*)d_in[2];
  const float* Wgate    = (const float*)d_in[3];
  const float* bgate    = (const float*)d_in[4];
  const float* Wout     = (const float*)d_in[5];
  const float* bout     = (const float*)d_in[6];
  const float* pos_bias = (const float*)d_in[7];
  const int*   offsets  = (const int*)d_in[8];
  float* out = (float*)d_out;
  __bf16* wsb = (__bf16*)d_ws;

  void* args[] = {(void*)&x, (void*)&Wqkv, (void*)&bqkv, (void*)&Wgate,
                  (void*)&bgate, (void*)&Wout, (void*)&bout, (void*)&pos_bias,
                  (void*)&offsets, (void*)&out, (void*)&wsb};
  hipError_t e = hipLaunchCooperativeKernel((const void*)fused_all,
                                            dim3(256), dim3(512), args, 0, stream);
  if (e != hipSuccess) {
    // Fallback: 4-kernel path (identical algorithms)
    __bf16* xb       = wsb;
    __bf16* Wqkvb    = xb    + (size_t)SEQ_N * DIM;
    __bf16* Wgateb   = Wqkvb + (size_t)3 * DIM * DIM;
    __bf16* Woutb    = Wgateb + (size_t)DIM * DIM;
    __bf16* qkvg     = Woutb + (size_t)DIM * DIM;
    __bf16* flatgate = qkvg  + (size_t)SEQ_N * LDQ;

    cvt_all<<<dim3(E4 / 2048), dim3(256), 0, stream>>>(x, Wqkv, Wgate, Wout, xb);
    gemm_bt2<128, 256, 64, 2, 4, 16, 16, __bf16>
        <<<dim3(16, 16), dim3(512), 0, stream>>>(
        xb, Wqkvb, Wgateb, bqkv, bgate, 3 * DIM, qkvg, LDQ, DIM);
    attn_mfma<<<dim3((SEQ_N / NT) * NHEAD), dim3(256), 0, stream>>>(
        qkvg, pos_bias, offsets, flatgate);
    gemm_bt2<64, 128, 64, 2, 2, 8, 32, float>
        <<<dim3(8, 32), dim3(256), 0, stream>>>(
        flatgate, Woutb, Woutb, bout, bout, DIM, out, DIM, DIM);
  }
}

// Round 6
// 148.053 us; speedup vs baseline: 1.7917x; 1.7917x over previous
//
#include <hip/hip_runtime.h>
#include <hip/hip_bf16.h>

// Problem constants (B=1, N=2048, D=1024, H=16, HD=64; NO=74 offsets)
#define SEQ_N 2048
#define DIM   1024
#define NHEAD 16
#define HDIM  64
#define LDQ   4096   // qkvg row stride: [q | k | v | gatepre]
#define NOFF  74     // 65 dense (0..64) + 9 dyadic
#define NDENSE 65
#define NJ    224    // 80 dense rows + 9*16 dyadic rows
#define NT    16     // n-rows per attention block
#define PST   232    // Pd row stride (padded, 16B-aligned)
#define QST   88     // Qbuf row stride (16B-aligned)

typedef __attribute__((ext_vector_type(8)))  __bf16 bv8;
typedef __attribute__((ext_vector_type(4)))  __bf16 bv4;
typedef __attribute__((ext_vector_type(4)))  float  f32x4;
typedef __attribute__((ext_vector_type(16))) float  f32x16;

typedef __attribute__((address_space(3))) void as3_void;
typedef __attribute__((address_space(1))) void as1_void;

// async global->LDS 16B copy. LDS dest must be wave-uniform base + lane*16.
__device__ __forceinline__ void async16(const void* g, void* l) {
  __builtin_amdgcn_global_load_lds((as1_void*)(unsigned long long)g,
                                   (as3_void*)l, 16, 0, 0);
}

// ---------------------------------------------------------------------------
// GEMM with in-staging fp32->bf16 conversion (R16). C = A*B^T + bias.
// - B (weights) is ALWAYS fp32 global, reg-staged: global_load float4 x2 ->
//   (__bf16) casts -> one ds_write_b128 per 8-elem chunk. Same LDS layout +
//   XOR chunk-swizzle as the async16 path (linear dest, swizzled source col).
// - A is fp32 reg-staged (AF32=true, gemm1: A=x) or bf16 async16
//   (AF32=false, gemm3: A=flatgate).
// - T14 split: loads(t+1) issued BEFORE compute(t); vmcnt drains via the
//   ds_write data-dep AFTER compute; ONE __syncthreads per K-step.
// - Inner: v_mfma_f32_32x32x16_bf16 (A/B: m=lane&31, k=8*(lane>>5)+i; C/D:
//   col=lane&31, row=(reg&3)+8*(reg>>2)+4*(lane>>5) [m74/m101 verified]).
// - T1 XCD chunked swizzle (bijective: NWG%8==0), column-major work order.
// Numerics: fp32->bf16 cast identical to the old cvt kernel; K-order (KT=64
// ascending) identical -> outputs bit-identical to the R2-verified path.
// ---------------------------------------------------------------------------
template <int BM_, int BN_, int KT_, int WM, int WN, int GX, int GY,
          bool AF32, typename OutT>
__global__ __launch_bounds__(WM * WN * 64) void gemm_cvt(
    const void* __restrict__ Av, const float* __restrict__ B1,
    const float* __restrict__ B2, const float* __restrict__ bias1,
    const float* __restrict__ bias2, int Nsplit,
    OutT* __restrict__ C, int ldc, int K) {
  constexpr int NTHR = WM * WN * 64;
  constexpr int NI  = BM_ / (WM * 32);
  constexpr int NJ_ = BN_ / (WN * 32);
  constexpr int CA = BM_ * KT_ / 8;        // A 8-elem chunks per step
  constexpr int CB = BN_ * KT_ / 8;        // B 8-elem chunks per step
  constexpr int NCA = CA / NTHR;
  constexpr int NCB = CB / NTHR;
  constexpr int CPR = KT_ / 8;             // chunks per row
  constexpr int BUF = (BM_ + BN_) * KT_;   // elems per dbuf half
  static_assert(CA % NTHR == 0 && CB % NTHR == 0, "stage divisibility");

  __shared__ __attribute__((aligned(16))) __bf16 smem[2 * BUF];

  const int tid  = threadIdx.x;
  const int lane = tid & 63;
  const int wave = tid >> 6;
  const int wm = wave / WN, wn = wave % WN;
  const int m31 = lane & 31;
  const int h1  = lane >> 5;
  const int l7  = lane & 7;

  constexpr int NWG = GX * GY;
  const int bid  = blockIdx.y * GX + blockIdx.x;
  const int work = (bid & 7) * (NWG >> 3) + (bid >> 3);
  const int bn0 = (work / GY) * BN_;       // column-major work order
  const int bm0 = (work % GY) * BM_;

  const float* Bp;
  const float* biasp;
  if (bn0 < Nsplit) { Bp = B1 + (size_t)bn0 * K;            biasp = bias1 + bn0; }
  else              { Bp = B2 + (size_t)(bn0 - Nsplit) * K; biasp = bias2 + (bn0 - Nsplit); }
  const float*  Afp = (const float*)Av  + (AF32 ? (size_t)bm0 * K : 0);
  const __bf16* Abf = (const __bf16*)Av + (AF32 ? 0 : (size_t)bm0 * K);

  f32x16 acc[NI][NJ_] = {};

  float4 ra[AF32 ? NCA : 1][2];            // staged A (fp32 path)
  float4 rb[NCB][2];                       // staged B (always fp32)

  // issue global loads for K-step at ktoff (A: only if AF32; else async16
  // direct into buf[sel])
  auto load_step = [&](int ktoff, int sel_) {
    if constexpr (AF32) {
#pragma unroll
      for (int ci = 0; ci < NCA; ++ci) {
        int c = ci * NTHR + tid;
        int rr = c / CPR, qq = c % CPR;
        int qs = qq ^ (rr & 7);
        const float* g = Afp + (size_t)rr * K + ktoff + qs * 8;
        ra[ci][0] = *(const float4*)g;
        ra[ci][1] = *(const float4*)(g + 4);
      }
    } else {
#pragma unroll
      for (int ci = 0; ci < NCA; ++ci) {
        int c = ci * NTHR + tid;
        int rr = c / CPR, qq = c % CPR;
        int qs = qq ^ (rr & 7);
        async16(Abf + (size_t)rr * K + ktoff + qs * 8,
                smem + sel_ * BUF + c * 8);
      }
    }
#pragma unroll
    for (int ci = 0; ci < NCB; ++ci) {
      int cb = ci * NTHR + tid;
      int rr = cb / CPR, qq = cb % CPR;
      int qs = qq ^ (rr & 7);
      const float* g = Bp + (size_t)rr * K + ktoff + qs * 8;
      rb[ci][0] = *(const float4*)g;
      rb[ci][1] = *(const float4*)(g + 4);
    }
  };

  // convert staged regs -> bf16, write to LDS buf[sel] (linear chunk dest)
  auto write_step = [&](int sel_) {
    if constexpr (AF32) {
#pragma unroll
      for (int ci = 0; ci < NCA; ++ci) {
        int c = ci * NTHR + tid;
        bv8 ov;
        ov[0] = (__bf16)ra[ci][0].x; ov[1] = (__bf16)ra[ci][0].y;
        ov[2] = (__bf16)ra[ci][0].z; ov[3] = (__bf16)ra[ci][0].w;
        ov[4] = (__bf16)ra[ci][1].x; ov[5] = (__bf16)ra[ci][1].y;
        ov[6] = (__bf16)ra[ci][1].z; ov[7] = (__bf16)ra[ci][1].w;
        *(bv8*)(smem + sel_ * BUF + c * 8) = ov;
      }
    }
#pragma unroll
    for (int ci = 0; ci < NCB; ++ci) {
      int cb = ci * NTHR + tid;
      bv8 ov;
      ov[0] = (__bf16)rb[ci][0].x; ov[1] = (__bf16)rb[ci][0].y;
      ov[2] = (__bf16)rb[ci][0].z; ov[3] = (__bf16)rb[ci][0].w;
      ov[4] = (__bf16)rb[ci][1].x; ov[5] = (__bf16)rb[ci][1].y;
      ov[6] = (__bf16)rb[ci][1].z; ov[7] = (__bf16)rb[ci][1].w;
      *(bv8*)(smem + sel_ * BUF + BM_ * KT_ + cb * 8) = ov;
    }
  };

  // prologue: stage K-step 0 into buffer 0
  load_step(0, 0);
  write_step(0);
  __syncthreads();   // drains async16 (vmcnt) + ds_writes -> buf0 ready

  const int NSTEP = K / KT_;
  int sel = 0;
  for (int t = 0; t < NSTEP; ++t) {
    // T14 issue-early: loads for t+1 go in flight before compute(t)
    if (t + 1 < NSTEP) load_step((t + 1) * KT_, sel ^ 1);

#pragma unroll
    for (int kk = 0; kk < KT_ / 16; ++kk) {
      const int qs = ((kk * 2 + h1) ^ l7) * 8;
      bv8 af[NI], bfr[NJ_];
#pragma unroll
      for (int i = 0; i < NI; ++i)
        af[i] = *(const bv8*)(smem + sel * BUF +
                              (wm * (BM_ / WM) + i * 32 + m31) * KT_ + qs);
#pragma unroll
      for (int j = 0; j < NJ_; ++j)
        bfr[j] = *(const bv8*)(smem + sel * BUF + BM_ * KT_ +
                               (wn * (BN_ / WN) + j * 32 + m31) * KT_ + qs);
#pragma unroll
      for (int i = 0; i < NI; ++i)
#pragma unroll
        for (int j = 0; j < NJ_; ++j)
          acc[i][j] = __builtin_amdgcn_mfma_f32_32x32x16_bf16(af[i], bfr[j], acc[i][j], 0, 0, 0);
    }

    // T14 write-late: cvt+ds_write after compute (loads landed during MFMA).
    // Target buf[sel^1] was last read in step t-1 (barrier-protected).
    if (t + 1 < NSTEP) write_step(sel ^ 1);

    __syncthreads();   // publish buf[sel^1]; protect buf[sel] for next write
    sel ^= 1;
  }

#pragma unroll
  for (int i = 0; i < NI; ++i) {
#pragma unroll
    for (int j = 0; j < NJ_; ++j) {
      int ccol = wn * (BN_ / WN) + j * 32 + m31;
      float b = biasp[ccol];
#pragma unroll
      for (int reg = 0; reg < 16; ++reg) {
        int row = bm0 + wm * (BM_ / WM) + i * 32 + (reg & 3) + 8 * (reg >> 2) + 4 * h1;
        C[(size_t)row * ldc + bn0 + ccol] = (OutT)(acc[i][j][reg] + b);
      }
    }
  }
}

// ---------------------------------------------------------------------------
// MFMA-tile attention + gate. (R2-verified, unchanged)
// V staged into [j/4][d/16][4][16] SUBTILED LDS layout (source-side index
// permutation only -- async16 dest stays linear, m173 pattern); Phase 3 reads
// the B-fragment with ds_read_b64_tr_b16 (T10): 2 tr reads per kt.
// Subtiled elem addr: V[j][d] @ (j>>2)*256 + (d>>4)*64 + (j&3)*16 + (d&15).
// ---------------------------------------------------------------------------
__global__ __launch_bounds__(256) void attn_mfma(
    const __bf16* __restrict__ qkv,      // [SEQ_N x LDQ]
    const float* __restrict__ pos_bias,  // [NOFF x NHEAD]
    const int* __restrict__ offsets,     // [NOFF]
    __bf16* __restrict__ fg) {
  const int n0 = (blockIdx.x >> 4) * NT;
  const int h  = blockIdx.x & 15;
  const int tid = threadIdx.x;
  const int lane = tid & 63;
  const int w = tid >> 6;
  const int fr = lane & 15, fq = lane >> 4;
  const int fr7 = fr & 7;

  __shared__ __attribute__((aligned(16))) __bf16 KVbuf[NJ * HDIM];  // 28672 B
  __shared__ __attribute__((aligned(16))) __bf16 Qbuf[NT * QST];    // 2816 B
  __shared__ __attribute__((aligned(16))) float  Sbuf[NT][80];      // 5120 B
  __shared__ __attribute__((aligned(16))) __bf16 Pd[NT * PST];      // 7424 B
  __shared__ float inv_l[NT];

  const int ch = lane & 7;
  const int rowin = lane >> 3;          // 0..7, equals (row index)&7

  // --- Phase 0: stage Q, zero Pd, async-stage K (swizzled chunks) ---
  if (tid < 128) {
    int ni = tid >> 3, cq = tid & 7;
    bv8 q = *(const bv8*)(qkv + (size_t)(n0 + ni) * LDQ + h * HDIM + cq * 8);
    *(bv8*)(Qbuf + ni * QST + cq * 8) = q;
  }
#pragma unroll
  for (int c0 = 0; c0 < NT * PST / 8; c0 += 256) {
    int c = c0 + tid;
    if (c < NT * PST / 8) *(uint4*)(Pd + c * 8) = make_uint4(0, 0, 0, 0);
  }
  {
    int chs = ch ^ rowin;           // swizzled k-chunk for K staging
#pragma unroll
    for (int it = 0; it < 7; ++it) {
      int jbase = it * 32 + w * 8;
      int j = jbase + rowin;
      int g;
      if (j < 80) g = n0 - 64 + j;
      else { int jj = j - 80; g = n0 - offsets[NDENSE + (jj >> 4)] + (jj & 15); }
      if (g < 0) g = 0;   // clamp; masked later
      async16(qkv + (size_t)g * LDQ + DIM + h * HDIM + chs * 8,
              KVbuf + jbase * HDIM + lane * 8);
    }
  }
  __syncthreads();

  // --- Phase 1: scores via MFMA, scatter banded entries to Sbuf ---
  for (int jb = w; jb < 14; jb += 4) {
    f32x4 acc = {};
#pragma unroll
    for (int kk = 0; kk < 2; ++kk) {
      bv8 a = *(const bv8*)(Qbuf + fr * QST + kk * 32 + fq * 8);
      bv8 b = *(const bv8*)(KVbuf + (jb * 16 + fr) * HDIM + ((kk * 4 + fq) ^ fr7) * 8);
      acc = __builtin_amdgcn_mfma_f32_16x16x32_bf16(a, b, acc, 0, 0, 0);
    }
    int j = jb * 16 + fr;           // K row this lane's column maps to
    if (jb < 5) {                   // dense region
      bool gvalid = (n0 - 64 + j) >= 0;
#pragma unroll
      for (int r = 0; r < 4; ++r) {
        int ni = fq * 4 + r;
        int o = ni + 64 - j;
        if (o >= 0 && o < NDENSE)
          Sbuf[ni][o] = gvalid ? acc[r] : -3.0e38f;
      }
    } else {                        // dyadic: only diagonal entries used
      int jj = j - 80;
      int s = jj >> 4, tni = jj & 15;
      int r = tni - fq * 4;
      if (r >= 0 && r < 4) {
        bool gvalid = (n0 + tni - offsets[NDENSE + s]) >= 0;
        Sbuf[tni][NDENSE + s] = gvalid ? acc[r] : -3.0e38f;
      }
    }
  }
  __syncthreads();   // all K reads done -> KVbuf reusable; Sbuf published

  // --- stage V into KVbuf, SUBTILED layout; overlaps Phase-2 softmax ---
  {
#pragma unroll
    for (int it = 0; it < 7; ++it) {
      int jbase = it * 32 + w * 8;
      int jv = jbase + (lane >> 5) * 4 + ((lane >> 1) & 3);
      int dv = ((lane >> 3) & 3) * 16 + (lane & 1) * 8;
      int g;
      if (jv < 80) g = n0 - 64 + jv;
      else { int jj = jv - 80; g = n0 - offsets[NDENSE + (jj >> 4)] + (jj & 15); }
      if (g < 0) g = 0;
      async16(qkv + (size_t)g * LDQ + 2 * DIM + h * HDIM + dv,
              KVbuf + jbase * HDIM + lane * 8);
    }
  }

  // --- Phase 2: softmax (16 threads per row), banded P -> Pd (bf16) ---
  {
    int t = tid & 15, ni = tid >> 4;
    float sc5[5];
    float m = -3.0e38f;
#pragma unroll
    for (int k = 0; k < 5; ++k) {
      int o = t + k * 16;
      float v = -3.0e38f;
      if (o < NOFF) {
        float raw = Sbuf[ni][o];
        if (raw > -1.0e38f) v = raw * 0.125f + pos_bias[o * NHEAD + h];
      }
      sc5[k] = v;
      m = fmaxf(m, v);
    }
#pragma unroll
    for (int d = 1; d < 16; d <<= 1) m = fmaxf(m, __shfl_xor(m, d));
    float sum = 0.f;
#pragma unroll
    for (int k = 0; k < 5; ++k) {
      int o = t + k * 16;
      if (o < NOFF && sc5[k] > -1.0e38f) {
        float e = __expf(sc5[k] - m);
        sum += e;
        int j = (o < NDENSE) ? (ni + 64 - o) : (80 + (o - NDENSE) * 16 + ni);
        Pd[ni * PST + j] = (__bf16)e;
      }
    }
#pragma unroll
    for (int d = 1; d < 16; d <<= 1) sum += __shfl_xor(sum, d);
    if (t == 0) inv_l[ni] = 1.f / sum;
  }
  __syncthreads();   // drains V async16s (vmcnt 0) + publishes Pd/inv_l

  // --- Phase 3: PV via MFMA, B-fragment via 2x ds_read_b64_tr_b16 per kt.
  // waitcnt INSIDE the asm block (data dep orders the MFMA; no hoist hazard).
  {
    const int db = w;
    const unsigned vb0 = (unsigned)(size_t)(as3_void*)KVbuf
                       + fq * 1024 + db * 128 + fr * 8;
    f32x4 acc = {};
#pragma unroll
    for (int kt = 0; kt < 7; ++kt) {
      bv8 a = *(const bv8*)(Pd + fr * PST + kt * 32 + fq * 8);
      bv4 lo, hi;
      asm volatile("ds_read_b64_tr_b16 %0, %2 offset:%3\n\t"
                   "ds_read_b64_tr_b16 %1, %2 offset:%4\n\t"
                   "s_waitcnt lgkmcnt(0)"
                   : "=&v"(lo), "=&v"(hi)
                   : "v"(vb0), "i"(kt * 4096), "i"(kt * 4096 + 512));
      bv8 b;
#pragma unroll
      for (int jj = 0; jj < 4; ++jj) { b[jj] = lo[jj]; b[4 + jj] = hi[jj]; }
      acc = __builtin_amdgcn_mfma_f32_16x16x32_bf16(a, b, acc, 0, 0, 0);
    }
    int d = db * 16 + fr;
#pragma unroll
    for (int r = 0; r < 4; ++r) {
      int ni = fq * 4 + r;
      float o = acc[r] * inv_l[ni];
      float gp = (float)qkv[(size_t)(n0 + ni) * LDQ + 3 * DIM + h * HDIM + d];
      float gate = 1.f / (1.f + __expf(-gp));
      fg[(size_t)(n0 + ni) * DIM + h * HDIM + d] = (__bf16)(o * gate);
    }
  }
}

// ---------------------------------------------------------------------------
extern "C" void kernel_launch(void* const* d_in, const int* in_sizes, int n_in,
                              void* d_out, int out_size, void* d_ws, size_t ws_size,
                              hipStream_t stream) {
  const float* x        = (const float*)d_in[0];
  const float* Wqkv     = (const float*)d_in[1];
  const float* bqkv     = (const float*)d_in[2];
  const float* Wgate    = (const float*)d_in[3];
  const float* bgate    = (const float*)d_in[4];
  const float* Wout     = (const float*)d_in[5];
  const float* bout     = (const float*)d_in[6];
  const float* pos_bias = (const float*)d_in[7];
  const int*   offsets  = (const int*)d_in[8];
  float* out = (float*)d_out;

  // workspace layout (bf16): only the two true intermediates remain
  __bf16* qkvg     = (__bf16*)d_ws;                               // 2048x4096
  __bf16* flatgate = qkvg + (size_t)SEQ_N * LDQ;                  // 2048x1024

  // 1) [qkv | gate_pre] = x @ [Wqkv;Wgate]^T + [bqkv;bgate] -> bf16 qkvg.
  //    fp32 inputs converted in-staging (no cvt kernel, no ws round-trip).
  //    128x256 tile, 8 waves, KT=64, dbuf + T14 issue-early/write-late.
  gemm_cvt<128, 256, 64, 2, 4, 16, 16, true, __bf16>
      <<<dim3(16, 16), dim3(512), 0, stream>>>(
      (const void*)x, Wqkv, Wgate, bqkv, bgate, 3 * DIM, qkvg, LDQ, DIM);

  // 2) attention + sigmoid-gate fuse -> flatgate (bf16)
  attn_mfma<<<dim3((SEQ_N / NT) * NHEAD), dim3(256), 0, stream>>>(
      qkvg, pos_bias, offsets, flatgate);

  // 3) out = flatgate @ Wout^T + bout -> fp32 d_out.
  //    A (flatgate) bf16 async16-staged; B (Wout) fp32 converted in-staging.
  //    64x128 tile, 4 waves, KT=64, dbuf.
  gemm_cvt<64, 128, 64, 2, 2, 8, 32, false, float>
      <<<dim3(8, 32), dim3(256), 0, stream>>>(
      (const void*)flatgate, Wout, Wout, bout, bout, DIM, out, DIM, DIM);
}